// Round 1
// baseline (569.718 us; speedup 1.0000x reference)
//
#include <hip/hip_runtime.h>
#include <hip/hip_bf16.h>

typedef __attribute__((ext_vector_type(8))) short bf16x8;
typedef __attribute__((ext_vector_type(4))) float f32x4;

#define D_MODEL 768
#define N_HEADS 12
#define D_HEAD  64
#define SEQ     4096
#define BATCH   2
#define MROWS   (BATCH * SEQ)          // 8192
#define QKV_N   (3 * D_MODEL)          // 2304

// ---------------------------------------------------------------------------
// f32 -> bf16 conversion (vectorized, n multiple of 4)
// ---------------------------------------------------------------------------
__global__ __launch_bounds__(256) void f32_to_bf16(const float* __restrict__ in,
                                                   unsigned short* __restrict__ out,
                                                   int n4) {
    int i = blockIdx.x * blockDim.x + threadIdx.x;
    if (i >= n4) return;
    const float4 v = *(const float4*)(in + (size_t)i * 4);
    ushort4 o;
    o.x = __bfloat16_as_ushort(__float2bfloat16(v.x));
    o.y = __bfloat16_as_ushort(__float2bfloat16(v.y));
    o.z = __bfloat16_as_ushort(__float2bfloat16(v.z));
    o.w = __bfloat16_as_ushort(__float2bfloat16(v.w));
    *(ushort4*)(out + (size_t)i * 4) = o;
}

// ---------------------------------------------------------------------------
// GEMM: C[M,N] = A[M,K] * B[N,K]^T   (both operands K-major, bf16, f32 acc)
// 128x128 tile, BK=64, 4 waves (2x2), each wave 64x64 = 4x4 fragments 16x16.
// ---------------------------------------------------------------------------
#define BM 128
#define BN 128
#define BK 64

template <bool OUT_F32>
__global__ __launch_bounds__(256) void gemm_bt(const short* __restrict__ A,
                                               const short* __restrict__ B,
                                               float* __restrict__ Cf,
                                               unsigned short* __restrict__ Cb,
                                               int M, int N, int K) {
    __shared__ __align__(16) short As[BM][BK];
    __shared__ __align__(16) short Bs[BN][BK];

    const int tid  = threadIdx.x;
    const int m0   = blockIdx.y * BM;
    const int n0   = blockIdx.x * BN;
    const int w    = tid >> 6;
    const int lane = tid & 63;
    const int wr   = w >> 1, wc = w & 1;
    const int lr   = lane & 15, lhi = lane >> 4;

    f32x4 acc[4][4];
#pragma unroll
    for (int i = 0; i < 4; i++)
#pragma unroll
        for (int j = 0; j < 4; j++)
#pragma unroll
            for (int e = 0; e < 4; e++) acc[i][j][e] = 0.0f;

    for (int k0 = 0; k0 < K; k0 += BK) {
        __syncthreads();
#pragma unroll
        for (int s = 0; s < 4; ++s) {
            int seg = tid + s * 256;       // 0..1023
            int row = seg >> 3;            // 128 rows, 8 segs/row
            int kc  = (seg & 7) * 8;
            *(bf16x8*)&As[row][kc] = *(const bf16x8*)&A[(size_t)(m0 + row) * K + k0 + kc];
            *(bf16x8*)&Bs[row][kc] = *(const bf16x8*)&B[(size_t)(n0 + row) * K + k0 + kc];
        }
        __syncthreads();
#pragma unroll
        for (int c = 0; c < 2; ++c) {
            bf16x8 af[4], bfr[4];
#pragma unroll
            for (int mi = 0; mi < 4; mi++)
                af[mi] = *(const bf16x8*)&As[wr * 64 + mi * 16 + lr][c * 32 + lhi * 8];
#pragma unroll
            for (int ni = 0; ni < 4; ni++)
                bfr[ni] = *(const bf16x8*)&Bs[wc * 64 + ni * 16 + lr][c * 32 + lhi * 8];
#pragma unroll
            for (int mi = 0; mi < 4; mi++)
#pragma unroll
                for (int ni = 0; ni < 4; ni++)
                    acc[mi][ni] = __builtin_amdgcn_mfma_f32_16x16x32_bf16(af[mi], bfr[ni], acc[mi][ni], 0, 0, 0);
        }
    }

    // C/D layout: col = lane&15, row = (lane>>4)*4 + r   [m89]
#pragma unroll
    for (int mi = 0; mi < 4; mi++)
#pragma unroll
        for (int ni = 0; ni < 4; ni++)
#pragma unroll
            for (int r = 0; r < 4; r++) {
                int row = m0 + wr * 64 + mi * 16 + lhi * 4 + r;
                int col = n0 + wc * 64 + ni * 16 + lr;
                float v = acc[mi][ni][r];
                if (OUT_F32)
                    Cf[(size_t)row * N + col] = v;
                else
                    Cb[(size_t)row * N + col] = __bfloat16_as_ushort(__float2bfloat16(v));
            }
}

// ---------------------------------------------------------------------------
// Flash attention (causal). qkv: (B*T, 2304) bf16 [Q|K|V], out: (B*T,768) bf16
// Grid: (T/64, B*H). Block 256 = 4 waves; wave w owns q-rows q0+w*16..+15.
// KV tile 64. K staged [kk][d]; V staged transposed [d][kk].
// ---------------------------------------------------------------------------
__global__ __launch_bounds__(256) void attn_fwd(const short* __restrict__ qkv,
                                                unsigned short* __restrict__ out) {
    __shared__ __align__(16) short Ks[64][64];
    __shared__ __align__(16) short Vt[64][64];
    __shared__ __align__(16) short Ps[4][16][64];

    const int tid  = threadIdx.x;
    const int w    = tid >> 6;
    const int lane = tid & 63;
    const int lr   = lane & 15, lhi = lane >> 4;
    const int q0   = blockIdx.x * 64;
    const int bh   = blockIdx.y;
    const int b    = bh / N_HEADS, h = bh % N_HEADS;
    const size_t rowbase = (size_t)b * SEQ;

    // Q fragments held in registers for the whole kernel.
    bf16x8 qf[2];
    {
        int qrow = q0 + w * 16 + lr;
        const short* p = &qkv[(rowbase + qrow) * QKV_N + h * D_HEAD];
        qf[0] = *(const bf16x8*)&p[lhi * 8];
        qf[1] = *(const bf16x8*)&p[32 + lhi * 8];
    }

    float m_r[4], l_r[4];
    f32x4 oacc[4];
#pragma unroll
    for (int r = 0; r < 4; r++) { m_r[r] = -INFINITY; l_r[r] = 0.0f; }
#pragma unroll
    for (int nd = 0; nd < 4; nd++)
#pragma unroll
        for (int r = 0; r < 4; r++) oacc[nd][r] = 0.0f;

    for (int j0 = 0; j0 <= q0; j0 += 64) {
        const bool diag = (j0 == q0);
        __syncthreads();
        // ---- stage K tile and V^T tile ----
#pragma unroll
        for (int s = 0; s < 2; ++s) {
            int seg = tid + s * 256;        // 0..511 : 64 rows x 8 segs
            int row = seg >> 3;
            int kc  = (seg & 7) * 8;
            const size_t gr = (rowbase + j0 + row) * QKV_N + h * D_HEAD + kc;
            *(bf16x8*)&Ks[row][kc] = *(const bf16x8*)&qkv[gr + D_MODEL];
            bf16x8 vv = *(const bf16x8*)&qkv[gr + 2 * D_MODEL];
#pragma unroll
            for (int j = 0; j < 8; j++) Vt[kc + j][row] = vv[j];
        }
        __syncthreads();

        // ---- S = Q K^T (16 q-rows x 64 kv-cols per wave) ----
        f32x4 sa[4];
#pragma unroll
        for (int ni = 0; ni < 4; ni++)
#pragma unroll
            for (int e = 0; e < 4; e++) sa[ni][e] = 0.0f;
#pragma unroll
        for (int c = 0; c < 2; c++)
#pragma unroll
            for (int ni = 0; ni < 4; ni++) {
                bf16x8 kf = *(const bf16x8*)&Ks[ni * 16 + lr][c * 32 + lhi * 8];
                sa[ni] = __builtin_amdgcn_mfma_f32_16x16x32_bf16(qf[c], kf, sa[ni], 0, 0, 0);
            }

        // ---- online softmax ----
        float sv[4][4], mx[4];
#pragma unroll
        for (int r = 0; r < 4; r++) mx[r] = -INFINITY;
#pragma unroll
        for (int ni = 0; ni < 4; ni++)
#pragma unroll
            for (int r = 0; r < 4; r++) {
                float s = sa[ni][r] * 0.125f;   // 1/sqrt(64)
                if (diag) {
                    int col = ni * 16 + lr;
                    int row = w * 16 + lhi * 4 + r;
                    if (col > row) s = -INFINITY;
                }
                sv[ni][r] = s;
                mx[r] = fmaxf(mx[r], s);
            }
#pragma unroll
        for (int off = 1; off < 16; off <<= 1)
#pragma unroll
            for (int r = 0; r < 4; r++) mx[r] = fmaxf(mx[r], __shfl_xor(mx[r], off, 64));

        float corr[4];
#pragma unroll
        for (int r = 0; r < 4; r++) {
            float mn = fmaxf(m_r[r], mx[r]);
            corr[r] = __expf(m_r[r] - mn);
            m_r[r] = mn;
        }
        float rs[4];
#pragma unroll
        for (int r = 0; r < 4; r++) rs[r] = 0.0f;
        float pr[4][4];
#pragma unroll
        for (int ni = 0; ni < 4; ni++)
#pragma unroll
            for (int r = 0; r < 4; r++) {
                float p = __expf(sv[ni][r] - m_r[r]);
                pr[ni][r] = p;
                rs[r] += p;
            }
#pragma unroll
        for (int off = 1; off < 16; off <<= 1)
#pragma unroll
            for (int r = 0; r < 4; r++) rs[r] += __shfl_xor(rs[r], off, 64);
#pragma unroll
        for (int r = 0; r < 4; r++) l_r[r] = l_r[r] * corr[r] + rs[r];
#pragma unroll
        for (int nd = 0; nd < 4; nd++)
#pragma unroll
            for (int r = 0; r < 4; r++) oacc[nd][r] *= corr[r];

        // ---- P -> per-wave LDS (D-layout) then re-read as A-fragments ----
#pragma unroll
        for (int ni = 0; ni < 4; ni++)
#pragma unroll
            for (int r = 0; r < 4; r++)
                Ps[w][lhi * 4 + r][ni * 16 + lr] = (short)__bfloat16_as_ushort(__float2bfloat16(pr[ni][r]));

        // same-wave LDS ordering: compiler inserts lgkmcnt before reads
#pragma unroll
        for (int c = 0; c < 2; c++) {
            bf16x8 pa = *(const bf16x8*)&Ps[w][lr][c * 32 + lhi * 8];
#pragma unroll
            for (int nd = 0; nd < 4; nd++) {
                bf16x8 vb = *(const bf16x8*)&Vt[nd * 16 + lr][c * 32 + lhi * 8];
                oacc[nd] = __builtin_amdgcn_mfma_f32_16x16x32_bf16(pa, vb, oacc[nd], 0, 0, 0);
            }
        }
    }

    // ---- epilogue ----
#pragma unroll
    for (int nd = 0; nd < 4; nd++)
#pragma unroll
        for (int r = 0; r < 4; r++) {
            float v = oacc[nd][r] / l_r[r];
            int qrow = q0 + w * 16 + lhi * 4 + r;
            out[(rowbase + qrow) * D_MODEL + h * D_HEAD + nd * 16 + lr] =
                __bfloat16_as_ushort(__float2bfloat16(v));
        }
}

// ---------------------------------------------------------------------------
extern "C" void kernel_launch(void* const* d_in, const int* in_sizes, int n_in,
                              void* d_out, int out_size, void* d_ws, size_t ws_size,
                              hipStream_t stream) {
    const float* x     = (const float*)d_in[0];
    const float* w_qkv = (const float*)d_in[1];
    const float* w_out = (const float*)d_in[2];
    float* outp        = (float*)d_out;

    char* ws = (char*)d_ws;
    size_t off = 0;
    auto alloc = [&](size_t bytes) -> void* {
        void* p = ws + off;
        off = (off + bytes + 255) & ~(size_t)255;
        return p;
    };
    unsigned short* xb    = (unsigned short*)alloc((size_t)MROWS * D_MODEL * 2);
    unsigned short* wqkvb = (unsigned short*)alloc((size_t)QKV_N * D_MODEL * 2);
    unsigned short* woutb = (unsigned short*)alloc((size_t)D_MODEL * D_MODEL * 2);
    unsigned short* qkvb  = (unsigned short*)alloc((size_t)MROWS * QKV_N * 2);
    unsigned short* attnb = (unsigned short*)alloc((size_t)MROWS * D_MODEL * 2);

    // converts
    {
        int n4 = MROWS * D_MODEL / 4;
        f32_to_bf16<<<(n4 + 255) / 256, 256, 0, stream>>>(x, xb, n4);
        n4 = QKV_N * D_MODEL / 4;
        f32_to_bf16<<<(n4 + 255) / 256, 256, 0, stream>>>(w_qkv, wqkvb, n4);
        n4 = D_MODEL * D_MODEL / 4;
        f32_to_bf16<<<(n4 + 255) / 256, 256, 0, stream>>>(w_out, woutb, n4);
    }

    // qkv = x @ w_qkv^T   (M=8192, N=2304, K=768) -> bf16
    gemm_bt<false><<<dim3(QKV_N / BN, MROWS / BM), 256, 0, stream>>>(
        (const short*)xb, (const short*)wqkvb, nullptr, qkvb, MROWS, QKV_N, D_MODEL);

    // attention
    attn_fwd<<<dim3(SEQ / 64, BATCH * N_HEADS), 256, 0, stream>>>((const short*)qkvb, attnb);

    // out = attn @ w_out^T  (M=8192, N=768, K=768) -> f32
    gemm_bt<true><<<dim3(D_MODEL / BN, MROWS / BM), 256, 0, stream>>>(
        (const short*)attnb, (const short*)woutb, outp, nullptr, MROWS, D_MODEL, D_MODEL);
}

// Round 3
// 386.775 us; speedup vs baseline: 1.4730x; 1.4730x over previous
//
#include <hip/hip_runtime.h>
#include <hip/hip_bf16.h>

typedef __attribute__((ext_vector_type(8))) short bf16x8;
typedef __attribute__((ext_vector_type(4))) float f32x4;

#define D_MODEL 768
#define N_HEADS 12
#define D_HEAD  64
#define SEQ     4096
#define BATCH   2
#define MROWS   (BATCH * SEQ)          // 8192
#define QKV_N   (3 * D_MODEL)          // 2304
#define NTILES  (SEQ / 64)             // 64

// ---------------------------------------------------------------------------
// f32 -> bf16 conversion (vectorized, n multiple of 4)
// ---------------------------------------------------------------------------
__global__ __launch_bounds__(256) void f32_to_bf16(const float* __restrict__ in,
                                                   unsigned short* __restrict__ out,
                                                   int n4) {
    int i = blockIdx.x * blockDim.x + threadIdx.x;
    if (i >= n4) return;
    const float4 v = *(const float4*)(in + (size_t)i * 4);
    ushort4 o;
    o.x = __bfloat16_as_ushort(__float2bfloat16(v.x));
    o.y = __bfloat16_as_ushort(__float2bfloat16(v.y));
    o.z = __bfloat16_as_ushort(__float2bfloat16(v.z));
    o.w = __bfloat16_as_ushort(__float2bfloat16(v.w));
    *(ushort4*)(out + (size_t)i * 4) = o;
}

// ---------------------------------------------------------------------------
// GEMM: C[M,N] = A[M,K] * B[N,K]^T   (both operands K-major, bf16, f32 acc)
// 128x128 tile, BK=64, 4 waves (2x2), each wave 64x64 = 4x4 fragments 16x16.
// ---------------------------------------------------------------------------
#define BM 128
#define BN 128
#define BK 64

template <bool OUT_F32>
__global__ __launch_bounds__(256) void gemm_bt(const short* __restrict__ A,
                                               const short* __restrict__ B,
                                               float* __restrict__ Cf,
                                               unsigned short* __restrict__ Cb,
                                               int M, int N, int K) {
    __shared__ __align__(16) short As[BM][BK];
    __shared__ __align__(16) short Bs[BN][BK];

    const int tid  = threadIdx.x;
    const int m0   = blockIdx.y * BM;
    const int n0   = blockIdx.x * BN;
    const int w    = tid >> 6;
    const int lane = tid & 63;
    const int wr   = w >> 1, wc = w & 1;
    const int lr   = lane & 15, lhi = lane >> 4;

    f32x4 acc[4][4];
#pragma unroll
    for (int i = 0; i < 4; i++)
#pragma unroll
        for (int j = 0; j < 4; j++)
#pragma unroll
            for (int e = 0; e < 4; e++) acc[i][j][e] = 0.0f;

    for (int k0 = 0; k0 < K; k0 += BK) {
        __syncthreads();
#pragma unroll
        for (int s = 0; s < 4; ++s) {
            int seg = tid + s * 256;       // 0..1023
            int row = seg >> 3;            // 128 rows, 8 segs/row
            int kc  = (seg & 7) * 8;
            *(bf16x8*)&As[row][kc] = *(const bf16x8*)&A[(size_t)(m0 + row) * K + k0 + kc];
            *(bf16x8*)&Bs[row][kc] = *(const bf16x8*)&B[(size_t)(n0 + row) * K + k0 + kc];
        }
        __syncthreads();
#pragma unroll
        for (int c = 0; c < 2; ++c) {
            bf16x8 af[4], bfr[4];
#pragma unroll
            for (int mi = 0; mi < 4; mi++)
                af[mi] = *(const bf16x8*)&As[wr * 64 + mi * 16 + lr][c * 32 + lhi * 8];
#pragma unroll
            for (int ni = 0; ni < 4; ni++)
                bfr[ni] = *(const bf16x8*)&Bs[wc * 64 + ni * 16 + lr][c * 32 + lhi * 8];
#pragma unroll
            for (int mi = 0; mi < 4; mi++)
#pragma unroll
                for (int ni = 0; ni < 4; ni++)
                    acc[mi][ni] = __builtin_amdgcn_mfma_f32_16x16x32_bf16(af[mi], bfr[ni], acc[mi][ni], 0, 0, 0);
        }
    }

    // C/D layout: col = lane&15, row = (lane>>4)*4 + r   [m89]
#pragma unroll
    for (int mi = 0; mi < 4; mi++)
#pragma unroll
        for (int ni = 0; ni < 4; ni++)
#pragma unroll
            for (int r = 0; r < 4; r++) {
                int row = m0 + wr * 64 + mi * 16 + lhi * 4 + r;
                int col = n0 + wc * 64 + ni * 16 + lr;
                float v = acc[mi][ni][r];
                if (OUT_F32)
                    Cf[(size_t)row * N + col] = v;
                else
                    Cb[(size_t)row * N + col] = __bfloat16_as_ushort(__float2bfloat16(v));
            }
}

// ---------------------------------------------------------------------------
// Flash attention (causal), paired q-tiles for load balance.
// Block = 256 thr = 4 waves; wave w owns q-rows [w*16, w*16+16) of each q-tile.
// Block (i, bh) handles q-tiles i and 63-i: one staged KV tile feeds both.
// LDS rows padded to 72 elems (144B) to kill bank conflicts.
// ---------------------------------------------------------------------------
#define LDP 72

struct QState {
    bf16x8 qf[2];
    float  m_r[4], l_r[4];
    f32x4  oacc[4];
};

__device__ __forceinline__ void attn_tile(QState& st,
                                          const short (*Ks)[LDP],
                                          const short (*Vt)[LDP],
                                          short (*Psw)[LDP],   // [16][LDP] this wave's P buffer
                                          bool diag, int w, int lr, int lhi) {
    // ---- S = Q K^T (16 q-rows x 64 kv-cols) ----
    f32x4 sa[4];
#pragma unroll
    for (int ni = 0; ni < 4; ni++)
#pragma unroll
        for (int e = 0; e < 4; e++) sa[ni][e] = 0.0f;
#pragma unroll
    for (int c = 0; c < 2; c++)
#pragma unroll
        for (int ni = 0; ni < 4; ni++) {
            bf16x8 kf = *(const bf16x8*)&Ks[ni * 16 + lr][c * 32 + lhi * 8];
            sa[ni] = __builtin_amdgcn_mfma_f32_16x16x32_bf16(st.qf[c], kf, sa[ni], 0, 0, 0);
        }

    // ---- online softmax ----
    float sv[4][4], mx[4];
#pragma unroll
    for (int r = 0; r < 4; r++) mx[r] = -INFINITY;
#pragma unroll
    for (int ni = 0; ni < 4; ni++)
#pragma unroll
        for (int r = 0; r < 4; r++) {
            float s = sa[ni][r] * 0.125f;   // 1/sqrt(64)
            if (diag) {
                int col = ni * 16 + lr;
                int row = w * 16 + lhi * 4 + r;   // q-row within the 64-row q-tile
                if (col > row) s = -INFINITY;
            }
            sv[ni][r] = s;
            mx[r] = fmaxf(mx[r], s);
        }
    // row is spread across lanes differing in bits 0..3 (lr)
#pragma unroll
    for (int off = 1; off < 16; off <<= 1)
#pragma unroll
        for (int r = 0; r < 4; r++) mx[r] = fmaxf(mx[r], __shfl_xor(mx[r], off, 64));

    float corr[4];
#pragma unroll
    for (int r = 0; r < 4; r++) {
        float mn = fmaxf(st.m_r[r], mx[r]);
        corr[r] = __expf(st.m_r[r] - mn);
        st.m_r[r] = mn;
    }
    float rs[4];
#pragma unroll
    for (int r = 0; r < 4; r++) rs[r] = 0.0f;
    float pr[4][4];
#pragma unroll
    for (int ni = 0; ni < 4; ni++)
#pragma unroll
        for (int r = 0; r < 4; r++) {
            float p = __expf(sv[ni][r] - st.m_r[r]);
            pr[ni][r] = p;
            rs[r] += p;
        }
#pragma unroll
    for (int off = 1; off < 16; off <<= 1)
#pragma unroll
        for (int r = 0; r < 4; r++) rs[r] += __shfl_xor(rs[r], off, 64);
#pragma unroll
    for (int r = 0; r < 4; r++) st.l_r[r] = st.l_r[r] * corr[r] + rs[r];
#pragma unroll
    for (int nd = 0; nd < 4; nd++)
#pragma unroll
        for (int r = 0; r < 4; r++) st.oacc[nd][r] *= corr[r];

    // ---- P -> per-wave LDS (D-layout) then re-read as A-fragments ----
#pragma unroll
    for (int ni = 0; ni < 4; ni++)
#pragma unroll
        for (int r = 0; r < 4; r++)
            Psw[lhi * 4 + r][ni * 16 + lr] = (short)__bfloat16_as_ushort(__float2bfloat16(pr[ni][r]));

#pragma unroll
    for (int c = 0; c < 2; c++) {
        bf16x8 pa = *(const bf16x8*)&Psw[lr][c * 32 + lhi * 8];
#pragma unroll
        for (int nd = 0; nd < 4; nd++) {
            bf16x8 vb = *(const bf16x8*)&Vt[nd * 16 + lr][c * 32 + lhi * 8];
            st.oacc[nd] = __builtin_amdgcn_mfma_f32_16x16x32_bf16(pa, vb, st.oacc[nd], 0, 0, 0);
        }
    }
}

__global__ __launch_bounds__(256) void attn_fwd(const short* __restrict__ qkv,
                                                unsigned short* __restrict__ out) {
    __shared__ __align__(16) short Ks[64][LDP];
    __shared__ __align__(16) short Vt[64][LDP];
    __shared__ __align__(16) short Ps[4][16][LDP];

    const int tid  = threadIdx.x;
    const int w    = tid >> 6;
    const int lane = tid & 63;
    const int lr   = lane & 15, lhi = lane >> 4;
    const int i    = blockIdx.x;                 // 0..31
    const int bh   = blockIdx.y;
    const int b    = bh / N_HEADS, h = bh % N_HEADS;
    const size_t rowbase = (size_t)b * SEQ;

    const int qa0 = i * 64;                      // light q-tile
    const int qb0 = (NTILES - 1 - i) * 64;       // heavy q-tile

    QState sa_, sb_;
    {
        int qrowA = qa0 + w * 16 + lr;
        int qrowB = qb0 + w * 16 + lr;
        const short* pA = &qkv[(rowbase + qrowA) * QKV_N + h * D_HEAD];
        const short* pB = &qkv[(rowbase + qrowB) * QKV_N + h * D_HEAD];
        sa_.qf[0] = *(const bf16x8*)&pA[lhi * 8];
        sa_.qf[1] = *(const bf16x8*)&pA[32 + lhi * 8];
        sb_.qf[0] = *(const bf16x8*)&pB[lhi * 8];
        sb_.qf[1] = *(const bf16x8*)&pB[32 + lhi * 8];
    }
#pragma unroll
    for (int r = 0; r < 4; r++) {
        sa_.m_r[r] = -INFINITY; sa_.l_r[r] = 0.0f;
        sb_.m_r[r] = -INFINITY; sb_.l_r[r] = 0.0f;
    }
#pragma unroll
    for (int nd = 0; nd < 4; nd++)
#pragma unroll
        for (int r = 0; r < 4; r++) { sa_.oacc[nd][r] = 0.0f; sb_.oacc[nd][r] = 0.0f; }

    for (int j0 = 0; j0 <= qb0; j0 += 64) {
        __syncthreads();
        // ---- stage K tile and V^T tile ----
#pragma unroll
        for (int s = 0; s < 2; ++s) {
            int seg = tid + s * 256;        // 0..511 : 64 rows x 8 segs
            int row = seg >> 3;
            int kc  = (seg & 7) * 8;
            const size_t gr = (rowbase + j0 + row) * QKV_N + h * D_HEAD + kc;
            *(bf16x8*)&Ks[row][kc] = *(const bf16x8*)&qkv[gr + D_MODEL];
            bf16x8 vv = *(const bf16x8*)&qkv[gr + 2 * D_MODEL];
#pragma unroll
            for (int j = 0; j < 8; j++) Vt[kc + j][row] = vv[j];
        }
        __syncthreads();

        attn_tile(sb_, Ks, Vt, Ps[w], j0 == qb0, w, lr, lhi);
        if (j0 <= qa0)
            attn_tile(sa_, Ks, Vt, Ps[w], j0 == qa0, w, lr, lhi);
    }

    // ---- epilogue ----
#pragma unroll
    for (int r = 0; r < 4; r++) { sa_.l_r[r] = 1.0f / sa_.l_r[r]; sb_.l_r[r] = 1.0f / sb_.l_r[r]; }
#pragma unroll
    for (int nd = 0; nd < 4; nd++)
#pragma unroll
        for (int r = 0; r < 4; r++) {
            int qrowA = qa0 + w * 16 + lhi * 4 + r;
            int qrowB = qb0 + w * 16 + lhi * 4 + r;
            out[(rowbase + qrowA) * D_MODEL + h * D_HEAD + nd * 16 + lr] =
                __bfloat16_as_ushort(__float2bfloat16(sa_.oacc[nd][r] * sa_.l_r[r]));
            out[(rowbase + qrowB) * D_MODEL + h * D_HEAD + nd * 16 + lr] =
                __bfloat16_as_ushort(__float2bfloat16(sb_.oacc[nd][r] * sb_.l_r[r]));
        }
}

// ---------------------------------------------------------------------------
extern "C" void kernel_launch(void* const* d_in, const int* in_sizes, int n_in,
                              void* d_out, int out_size, void* d_ws, size_t ws_size,
                              hipStream_t stream) {
    const float* x     = (const float*)d_in[0];
    const float* w_qkv = (const float*)d_in[1];
    const float* w_out = (const float*)d_in[2];
    float* outp        = (float*)d_out;

    char* ws = (char*)d_ws;
    size_t off = 0;
    auto alloc = [&](size_t bytes) -> void* {
        void* p = ws + off;
        off = (off + bytes + 255) & ~(size_t)255;
        return p;
    };
    unsigned short* xb    = (unsigned short*)alloc((size_t)MROWS * D_MODEL * 2);
    unsigned short* wqkvb = (unsigned short*)alloc((size_t)QKV_N * D_MODEL * 2);
    unsigned short* woutb = (unsigned short*)alloc((size_t)D_MODEL * D_MODEL * 2);
    unsigned short* qkvb  = (unsigned short*)alloc((size_t)MROWS * QKV_N * 2);
    unsigned short* attnb = (unsigned short*)alloc((size_t)MROWS * D_MODEL * 2);

    // converts
    {
        int n4 = MROWS * D_MODEL / 4;
        f32_to_bf16<<<(n4 + 255) / 256, 256, 0, stream>>>(x, xb, n4);
        n4 = QKV_N * D_MODEL / 4;
        f32_to_bf16<<<(n4 + 255) / 256, 256, 0, stream>>>(w_qkv, wqkvb, n4);
        n4 = D_MODEL * D_MODEL / 4;
        f32_to_bf16<<<(n4 + 255) / 256, 256, 0, stream>>>(w_out, woutb, n4);
    }

    // qkv = x @ w_qkv^T   (M=8192, N=2304, K=768) -> bf16
    gemm_bt<false><<<dim3(QKV_N / BN, MROWS / BM), 256, 0, stream>>>(
        (const short*)xb, (const short*)wqkvb, nullptr, qkvb, MROWS, QKV_N, D_MODEL);

    // attention (paired q-tiles: 32 x 24 blocks)
    attn_fwd<<<dim3(NTILES / 2, BATCH * N_HEADS), 256, 0, stream>>>((const short*)qkvb, attnb);

    // out = attn @ w_out^T  (M=8192, N=768, K=768) -> f32
    gemm_bt<true><<<dim3(D_MODEL / BN, MROWS / BM), 256, 0, stream>>>(
        (const short*)attnb, (const short*)woutb, outp, nullptr, MROWS, D_MODEL, D_MODEL);
}

// Round 4
// 304.561 us; speedup vs baseline: 1.8706x; 1.2699x over previous
//
#include <hip/hip_runtime.h>
#include <hip/hip_bf16.h>

typedef __attribute__((ext_vector_type(8))) short bf16x8;
typedef __attribute__((ext_vector_type(4))) float f32x4;

#define D_MODEL 768
#define N_HEADS 12
#define D_HEAD  64
#define SEQ     4096
#define BATCH   2
#define MROWS   (BATCH * SEQ)          // 8192
#define QKV_N   (3 * D_MODEL)          // 2304
#define NTILES  (SEQ / 64)             // 64

// ---------------------------------------------------------------------------
// f32 -> bf16 conversion (vectorized, n multiple of 4)
// ---------------------------------------------------------------------------
__global__ __launch_bounds__(256) void f32_to_bf16(const float* __restrict__ in,
                                                   unsigned short* __restrict__ out,
                                                   int n4) {
    int i = blockIdx.x * blockDim.x + threadIdx.x;
    if (i >= n4) return;
    const float4 v = *(const float4*)(in + (size_t)i * 4);
    ushort4 o;
    o.x = __bfloat16_as_ushort(__float2bfloat16(v.x));
    o.y = __bfloat16_as_ushort(__float2bfloat16(v.y));
    o.z = __bfloat16_as_ushort(__float2bfloat16(v.z));
    o.w = __bfloat16_as_ushort(__float2bfloat16(v.w));
    *(ushort4*)(out + (size_t)i * 4) = o;
}

// ---------------------------------------------------------------------------
// GEMM: C[M,N] = A[M,K] * B[N,K]^T  (bf16, f32 acc), 128x128 tile, BK=64.
// T2 XOR-swizzle: LDS granule (16B) index ^= (row&7) on write AND read.
// ---------------------------------------------------------------------------
#define BM 128
#define BN 128
#define BK 64

template <bool OUT_F32>
__global__ __launch_bounds__(256) void gemm_bt(const short* __restrict__ A,
                                               const short* __restrict__ B,
                                               float* __restrict__ Cf,
                                               unsigned short* __restrict__ Cb,
                                               int M, int N, int K) {
    __shared__ __align__(16) short As[BM][BK];
    __shared__ __align__(16) short Bs[BN][BK];

    const int tid  = threadIdx.x;
    const int m0   = blockIdx.y * BM;
    const int n0   = blockIdx.x * BN;
    const int w    = tid >> 6;
    const int lane = tid & 63;
    const int wr   = w >> 1, wc = w & 1;
    const int lr   = lane & 15, lhi = lane >> 4;

    f32x4 acc[4][4];
#pragma unroll
    for (int i = 0; i < 4; i++)
#pragma unroll
        for (int j = 0; j < 4; j++)
#pragma unroll
            for (int e = 0; e < 4; e++) acc[i][j][e] = 0.0f;

    for (int k0 = 0; k0 < K; k0 += BK) {
        __syncthreads();
#pragma unroll
        for (int s = 0; s < 4; ++s) {
            int seg = tid + s * 256;       // 0..1023
            int row = seg >> 3;            // 128 rows, 8 granules/row
            int g   = seg & 7;
            int dst = (g ^ (row & 7)) * 8; // T2 swizzle
            *(bf16x8*)&As[row][dst] = *(const bf16x8*)&A[(size_t)(m0 + row) * K + k0 + g * 8];
            *(bf16x8*)&Bs[row][dst] = *(const bf16x8*)&B[(size_t)(n0 + row) * K + k0 + g * 8];
        }
        __syncthreads();
#pragma unroll
        for (int c = 0; c < 2; ++c) {
            bf16x8 af[4], bfr[4];
#pragma unroll
            for (int mi = 0; mi < 4; mi++) {
                int row = wr * 64 + mi * 16 + lr;
                af[mi] = *(const bf16x8*)&As[row][((c * 4 + lhi) ^ (lr & 7)) * 8];
            }
#pragma unroll
            for (int ni = 0; ni < 4; ni++) {
                int row = wc * 64 + ni * 16 + lr;
                bfr[ni] = *(const bf16x8*)&Bs[row][((c * 4 + lhi) ^ (lr & 7)) * 8];
            }
#pragma unroll
            for (int mi = 0; mi < 4; mi++)
#pragma unroll
                for (int ni = 0; ni < 4; ni++)
                    acc[mi][ni] = __builtin_amdgcn_mfma_f32_16x16x32_bf16(af[mi], bfr[ni], acc[mi][ni], 0, 0, 0);
        }
    }

    // C/D layout: col = lane&15, row = (lane>>4)*4 + r
#pragma unroll
    for (int mi = 0; mi < 4; mi++)
#pragma unroll
        for (int ni = 0; ni < 4; ni++)
#pragma unroll
            for (int r = 0; r < 4; r++) {
                int row = m0 + wr * 64 + mi * 16 + lhi * 4 + r;
                int col = n0 + wc * 64 + ni * 16 + lr;
                float v = acc[mi][ni][r];
                if (OUT_F32)
                    Cf[(size_t)row * N + col] = v;
                else
                    Cb[(size_t)row * N + col] = __bfloat16_as_ushort(__float2bfloat16(v));
            }
}

// ---------------------------------------------------------------------------
// V transpose: qkv V-region (b,t,h,d) -> vt[bh*64+d][t]  (bf16)
// Block: one (bh, 64-row t-tile). LDS tile then coalesced b128 writes.
// ---------------------------------------------------------------------------
__global__ __launch_bounds__(256) void v_transpose(const short* __restrict__ qkv,
                                                   short* __restrict__ vt) {
    __shared__ short S[64][72];   // [t][d], pad 72 (scalar reads broadcast-friendly)
    const int tid = threadIdx.x;
    const int t0  = blockIdx.x * 64;
    const int bh  = blockIdx.y;
    const int b   = bh / N_HEADS, h = bh % N_HEADS;
#pragma unroll
    for (int s = 0; s < 2; s++) {
        int tl = (tid >> 3) + 32 * s, dg = tid & 7;
        *(bf16x8*)&S[tl][dg * 8] =
            *(const bf16x8*)&qkv[((size_t)(b * SEQ + t0 + tl)) * QKV_N + 2 * D_MODEL + h * D_HEAD + dg * 8];
    }
    __syncthreads();
#pragma unroll
    for (int ii = 0; ii < 2; ii++) {
        int d = (tid >> 3) + 32 * ii, tg = tid & 7;
        bf16x8 v;
#pragma unroll
        for (int j = 0; j < 8; j++) v[j] = S[tg * 8 + j][d];
        *(bf16x8*)&vt[((size_t)bh * 64 + d) * SEQ + t0 + tg * 8] = v;
    }
}

// ---------------------------------------------------------------------------
// Flash attention (causal), paired q-tiles, T2-swizzled LDS, T14 prefetch.
// Block 256 = 4 waves; wave w owns q-rows [w*16, w*16+16) of both q-tiles.
// ---------------------------------------------------------------------------
struct QState {
    bf16x8 qf[2];
    float  m_r[4], l_r[4];
    f32x4  oacc[4];
};

__device__ __forceinline__ void attn_tile(QState& st,
                                          const short (*Ks)[64],
                                          const short (*Vs)[64],
                                          short (*Psw)[64],
                                          bool diag, int w, int lr, int lhi) {
    const int swz = lr & 7;
    // ---- S = Q K^T ----
    f32x4 sa[4];
#pragma unroll
    for (int ni = 0; ni < 4; ni++)
#pragma unroll
        for (int e = 0; e < 4; e++) sa[ni][e] = 0.0f;
#pragma unroll
    for (int c = 0; c < 2; c++)
#pragma unroll
        for (int ni = 0; ni < 4; ni++) {
            bf16x8 kf = *(const bf16x8*)&Ks[ni * 16 + lr][((c * 4 + lhi) ^ swz) * 8];
            sa[ni] = __builtin_amdgcn_mfma_f32_16x16x32_bf16(st.qf[c], kf, sa[ni], 0, 0, 0);
        }

    // ---- online softmax (arrays reused to limit VGPR) ----
    float sv[4][4], mx[4];
#pragma unroll
    for (int r = 0; r < 4; r++) mx[r] = -INFINITY;
#pragma unroll
    for (int ni = 0; ni < 4; ni++)
#pragma unroll
        for (int r = 0; r < 4; r++) {
            float s = sa[ni][r] * 0.125f;   // 1/sqrt(64)
            if (diag) {
                int col = ni * 16 + lr;
                int row = w * 16 + lhi * 4 + r;
                if (col > row) s = -INFINITY;
            }
            sv[ni][r] = s;
            mx[r] = fmaxf(mx[r], s);
        }
#pragma unroll
    for (int off = 1; off < 16; off <<= 1)
#pragma unroll
        for (int r = 0; r < 4; r++) mx[r] = fmaxf(mx[r], __shfl_xor(mx[r], off, 64));

    float corr[4];
#pragma unroll
    for (int r = 0; r < 4; r++) {
        float mn = fmaxf(st.m_r[r], mx[r]);
        corr[r] = __expf(st.m_r[r] - mn);
        st.m_r[r] = mn;
    }
    float rs[4];
#pragma unroll
    for (int r = 0; r < 4; r++) rs[r] = 0.0f;
#pragma unroll
    for (int ni = 0; ni < 4; ni++)
#pragma unroll
        for (int r = 0; r < 4; r++) {
            float p = __expf(sv[ni][r] - st.m_r[r]);
            sv[ni][r] = p;                 // in-place: sv now holds P
            rs[r] += p;
        }
#pragma unroll
    for (int off = 1; off < 16; off <<= 1)
#pragma unroll
        for (int r = 0; r < 4; r++) rs[r] += __shfl_xor(rs[r], off, 64);
#pragma unroll
    for (int r = 0; r < 4; r++) st.l_r[r] = st.l_r[r] * corr[r] + rs[r];
#pragma unroll
    for (int nd = 0; nd < 4; nd++)
#pragma unroll
        for (int r = 0; r < 4; r++) st.oacc[nd][r] *= corr[r];

    // ---- P -> per-wave LDS (swizzled), re-read as A-fragments ----
#pragma unroll
    for (int ni = 0; ni < 4; ni++)
#pragma unroll
        for (int r = 0; r < 4; r++) {
            int row = lhi * 4 + r;
            int col = ni * 16 + lr;
            Psw[row][((col >> 3) ^ (row & 7)) * 8 + (col & 7)] =
                (short)__bfloat16_as_ushort(__float2bfloat16(sv[ni][r]));
        }

#pragma unroll
    for (int c = 0; c < 2; c++) {
        bf16x8 pa = *(const bf16x8*)&Psw[lr][((c * 4 + lhi) ^ swz) * 8];
#pragma unroll
        for (int nd = 0; nd < 4; nd++) {
            bf16x8 vb = *(const bf16x8*)&Vs[nd * 16 + lr][((c * 4 + lhi) ^ swz) * 8];
            st.oacc[nd] = __builtin_amdgcn_mfma_f32_16x16x32_bf16(pa, vb, st.oacc[nd], 0, 0, 0);
        }
    }
}

__global__ __launch_bounds__(256) void attn_fwd(const short* __restrict__ qkv,
                                                const short* __restrict__ vt,
                                                unsigned short* __restrict__ out) {
    __shared__ __align__(16) short Ks[64][64];   // K tile  [kv][d]  (swizzled granules)
    __shared__ __align__(16) short Vs[64][64];   // V^T tile [d][kv] (swizzled granules)
    __shared__ __align__(16) short Ps[4][16][64];

    const int tid  = threadIdx.x;
    const int w    = tid >> 6;
    const int lane = tid & 63;
    const int lr   = lane & 15, lhi = lane >> 4;
    const int i    = blockIdx.x;                 // 0..31
    const int bh   = blockIdx.y;
    const int b    = bh / N_HEADS, h = bh % N_HEADS;
    const size_t rowbase = (size_t)b * SEQ;
    const int srow = tid >> 3, sg = tid & 7;     // staging: row-within-seg, granule

    const int qa0 = i * 64;                      // light q-tile
    const int qb0 = (NTILES - 1 - i) * 64;       // heavy q-tile

    QState sa_, sb_;
    {
        int qrowA = qa0 + w * 16 + lr;
        int qrowB = qb0 + w * 16 + lr;
        const short* pA = &qkv[(rowbase + qrowA) * QKV_N + h * D_HEAD];
        const short* pB = &qkv[(rowbase + qrowB) * QKV_N + h * D_HEAD];
        sa_.qf[0] = *(const bf16x8*)&pA[lhi * 8];
        sa_.qf[1] = *(const bf16x8*)&pA[32 + lhi * 8];
        sb_.qf[0] = *(const bf16x8*)&pB[lhi * 8];
        sb_.qf[1] = *(const bf16x8*)&pB[32 + lhi * 8];
    }
#pragma unroll
    for (int r = 0; r < 4; r++) {
        sa_.m_r[r] = -INFINITY; sa_.l_r[r] = 0.0f;
        sb_.m_r[r] = -INFINITY; sb_.l_r[r] = 0.0f;
    }
#pragma unroll
    for (int nd = 0; nd < 4; nd++)
#pragma unroll
        for (int r = 0; r < 4; r++) { sa_.oacc[nd][r] = 0.0f; sb_.oacc[nd][r] = 0.0f; }

    // T14: prefetch tile 0 into registers
    bf16x8 kp[2], vp[2];
#pragma unroll
    for (int s = 0; s < 2; s++) {
        int row = srow + 32 * s;
        kp[s] = *(const bf16x8*)&qkv[(rowbase + 0 + row) * QKV_N + D_MODEL + h * D_HEAD + sg * 8];
        vp[s] = *(const bf16x8*)&vt[((size_t)bh * 64 + row) * SEQ + 0 + sg * 8];
    }

    for (int j0 = 0; j0 <= qb0; j0 += 64) {
        __syncthreads();   // prev tile's LDS consumers done
        // write prefetched tile -> LDS (T2 swizzle)
#pragma unroll
        for (int s = 0; s < 2; s++) {
            int row = srow + 32 * s;
            int dst = (sg ^ (row & 7)) * 8;
            *(bf16x8*)&Ks[row][dst] = kp[s];
            *(bf16x8*)&Vs[row][dst] = vp[s];
        }
        // issue next tile's loads (latency hides under compute below)
        {
            int jn = (j0 + 64 <= qb0) ? j0 + 64 : 0;
#pragma unroll
            for (int s = 0; s < 2; s++) {
                int row = srow + 32 * s;
                kp[s] = *(const bf16x8*)&qkv[(rowbase + jn + row) * QKV_N + D_MODEL + h * D_HEAD + sg * 8];
                vp[s] = *(const bf16x8*)&vt[((size_t)bh * 64 + row) * SEQ + jn + sg * 8];
            }
        }
        __syncthreads();   // LDS tile ready

        attn_tile(sb_, Ks, Vs, Ps[w], j0 == qb0, w, lr, lhi);
        if (j0 <= qa0)
            attn_tile(sa_, Ks, Vs, Ps[w], j0 == qa0, w, lr, lhi);
    }

    // ---- epilogue ----
#pragma unroll
    for (int r = 0; r < 4; r++) { sa_.l_r[r] = 1.0f / sa_.l_r[r]; sb_.l_r[r] = 1.0f / sb_.l_r[r]; }
#pragma unroll
    for (int nd = 0; nd < 4; nd++)
#pragma unroll
        for (int r = 0; r < 4; r++) {
            int qrowA = qa0 + w * 16 + lhi * 4 + r;
            int qrowB = qb0 + w * 16 + lhi * 4 + r;
            out[(rowbase + qrowA) * D_MODEL + h * D_HEAD + nd * 16 + lr] =
                __bfloat16_as_ushort(__float2bfloat16(sa_.oacc[nd][r] * sa_.l_r[r]));
            out[(rowbase + qrowB) * D_MODEL + h * D_HEAD + nd * 16 + lr] =
                __bfloat16_as_ushort(__float2bfloat16(sb_.oacc[nd][r] * sb_.l_r[r]));
        }
}

// ---------------------------------------------------------------------------
extern "C" void kernel_launch(void* const* d_in, const int* in_sizes, int n_in,
                              void* d_out, int out_size, void* d_ws, size_t ws_size,
                              hipStream_t stream) {
    const float* x     = (const float*)d_in[0];
    const float* w_qkv = (const float*)d_in[1];
    const float* w_out = (const float*)d_in[2];
    float* outp        = (float*)d_out;

    char* ws = (char*)d_ws;
    size_t off = 0;
    auto alloc = [&](size_t bytes) -> void* {
        void* p = ws + off;
        off = (off + bytes + 255) & ~(size_t)255;
        return p;
    };
    unsigned short* xb    = (unsigned short*)alloc((size_t)MROWS * D_MODEL * 2);  // also attn out
    unsigned short* wqkvb = (unsigned short*)alloc((size_t)QKV_N * D_MODEL * 2);
    unsigned short* woutb = (unsigned short*)alloc((size_t)D_MODEL * D_MODEL * 2);
    unsigned short* qkvb  = (unsigned short*)alloc((size_t)MROWS * QKV_N * 2);
    unsigned short* vtb   = (unsigned short*)alloc((size_t)BATCH * N_HEADS * D_HEAD * SEQ * 2);

    // converts
    {
        int n4 = MROWS * D_MODEL / 4;
        f32_to_bf16<<<(n4 + 255) / 256, 256, 0, stream>>>(x, xb, n4);
        n4 = QKV_N * D_MODEL / 4;
        f32_to_bf16<<<(n4 + 255) / 256, 256, 0, stream>>>(w_qkv, wqkvb, n4);
        n4 = D_MODEL * D_MODEL / 4;
        f32_to_bf16<<<(n4 + 255) / 256, 256, 0, stream>>>(w_out, woutb, n4);
    }

    // qkv = x @ w_qkv^T   (M=8192, N=2304, K=768) -> bf16
    gemm_bt<false><<<dim3(QKV_N / BN, MROWS / BM), 256, 0, stream>>>(
        (const short*)xb, (const short*)wqkvb, nullptr, qkvb, MROWS, QKV_N, D_MODEL);

    // V transpose: (b,t,h,d) -> [bh*64+d][t]
    v_transpose<<<dim3(SEQ / 64, BATCH * N_HEADS), 256, 0, stream>>>((const short*)qkvb, (short*)vtb);

    // attention (paired q-tiles), writes bf16 into xb (dead after QKV GEMM)
    attn_fwd<<<dim3(NTILES / 2, BATCH * N_HEADS), 256, 0, stream>>>(
        (const short*)qkvb, (const short*)vtb, xb);

    // out = attn @ w_out^T  (M=8192, N=768, K=768) -> f32
    gemm_bt<true><<<dim3(D_MODEL / BN, MROWS / BM), 256, 0, stream>>>(
        (const short*)xb, (const short*)woutb, outp, nullptr, MROWS, D_MODEL, D_MODEL);
}

// Round 5
// 246.075 us; speedup vs baseline: 2.3152x; 1.2377x over previous
//
#include <hip/hip_runtime.h>
#include <hip/hip_bf16.h>

typedef __attribute__((ext_vector_type(8))) short bf16x8;
typedef __attribute__((ext_vector_type(4))) float f32x4;

#define D_MODEL 768
#define N_HEADS 12
#define D_HEAD  64
#define SEQ     4096
#define BATCH   2
#define MROWS   (BATCH * SEQ)          // 8192
#define QKV_N   (3 * D_MODEL)          // 2304
#define NTILES  (SEQ / 64)             // 64
#define SCL     0.18033688011112042f   // (1/8) * log2(e)

// ---------------------------------------------------------------------------
// f32 -> bf16 conversion (vectorized, n multiple of 4)
// ---------------------------------------------------------------------------
__global__ __launch_bounds__(256) void f32_to_bf16(const float* __restrict__ in,
                                                   unsigned short* __restrict__ out,
                                                   int n4) {
    int i = blockIdx.x * blockDim.x + threadIdx.x;
    if (i >= n4) return;
    const float4 v = *(const float4*)(in + (size_t)i * 4);
    ushort4 o;
    o.x = __bfloat16_as_ushort(__float2bfloat16(v.x));
    o.y = __bfloat16_as_ushort(__float2bfloat16(v.y));
    o.z = __bfloat16_as_ushort(__float2bfloat16(v.z));
    o.w = __bfloat16_as_ushort(__float2bfloat16(v.w));
    *(ushort4*)(out + (size_t)i * 4) = o;
}

// ---------------------------------------------------------------------------
// GEMM: C[M,N] = A[M,K] * B[N,K]^T  (bf16, f32 acc), 128x128 tile, BK=64.
// T2 XOR-swizzle: LDS granule (16B) index ^= (row&7) on write AND read.
// ---------------------------------------------------------------------------
#define BM 128
#define BN 128
#define BK 64

template <bool OUT_F32>
__global__ __launch_bounds__(256) void gemm_bt(const short* __restrict__ A,
                                               const short* __restrict__ B,
                                               float* __restrict__ Cf,
                                               unsigned short* __restrict__ Cb,
                                               int M, int N, int K) {
    __shared__ __align__(16) short As[BM][BK];
    __shared__ __align__(16) short Bs[BN][BK];

    const int tid  = threadIdx.x;
    const int m0   = blockIdx.y * BM;
    const int n0   = blockIdx.x * BN;
    const int w    = tid >> 6;
    const int lane = tid & 63;
    const int wr   = w >> 1, wc = w & 1;
    const int lr   = lane & 15, lhi = lane >> 4;

    f32x4 acc[4][4];
#pragma unroll
    for (int i = 0; i < 4; i++)
#pragma unroll
        for (int j = 0; j < 4; j++)
#pragma unroll
            for (int e = 0; e < 4; e++) acc[i][j][e] = 0.0f;

    for (int k0 = 0; k0 < K; k0 += BK) {
        __syncthreads();
#pragma unroll
        for (int s = 0; s < 4; ++s) {
            int seg = tid + s * 256;       // 0..1023
            int row = seg >> 3;            // 128 rows, 8 granules/row
            int g   = seg & 7;
            int dst = (g ^ (row & 7)) * 8; // T2 swizzle
            *(bf16x8*)&As[row][dst] = *(const bf16x8*)&A[(size_t)(m0 + row) * K + k0 + g * 8];
            *(bf16x8*)&Bs[row][dst] = *(const bf16x8*)&B[(size_t)(n0 + row) * K + k0 + g * 8];
        }
        __syncthreads();
#pragma unroll
        for (int c = 0; c < 2; ++c) {
            bf16x8 af[4], bfr[4];
#pragma unroll
            for (int mi = 0; mi < 4; mi++) {
                int row = wr * 64 + mi * 16 + lr;
                af[mi] = *(const bf16x8*)&As[row][((c * 4 + lhi) ^ (lr & 7)) * 8];
            }
#pragma unroll
            for (int ni = 0; ni < 4; ni++) {
                int row = wc * 64 + ni * 16 + lr;
                bfr[ni] = *(const bf16x8*)&Bs[row][((c * 4 + lhi) ^ (lr & 7)) * 8];
            }
#pragma unroll
            for (int mi = 0; mi < 4; mi++)
#pragma unroll
                for (int ni = 0; ni < 4; ni++)
                    acc[mi][ni] = __builtin_amdgcn_mfma_f32_16x16x32_bf16(af[mi], bfr[ni], acc[mi][ni], 0, 0, 0);
        }
    }

    // C/D layout: col = lane&15, row = (lane>>4)*4 + r
#pragma unroll
    for (int mi = 0; mi < 4; mi++)
#pragma unroll
        for (int ni = 0; ni < 4; ni++)
#pragma unroll
            for (int r = 0; r < 4; r++) {
                int row = m0 + wr * 64 + mi * 16 + lhi * 4 + r;
                int col = n0 + wc * 64 + ni * 16 + lr;
                float v = acc[mi][ni][r];
                if (OUT_F32)
                    Cf[(size_t)row * N + col] = v;
                else
                    Cb[(size_t)row * N + col] = __bfloat16_as_ushort(__float2bfloat16(v));
            }
}

// ---------------------------------------------------------------------------
// V transpose: qkv V-region (b,t,h,d) -> vt[bh*64+d][t]  (bf16)
// ---------------------------------------------------------------------------
__global__ __launch_bounds__(256) void v_transpose(const short* __restrict__ qkv,
                                                   short* __restrict__ vt) {
    __shared__ short S[64][72];
    const int tid = threadIdx.x;
    const int t0  = blockIdx.x * 64;
    const int bh  = blockIdx.y;
    const int b   = bh / N_HEADS, h = bh % N_HEADS;
#pragma unroll
    for (int s = 0; s < 2; s++) {
        int tl = (tid >> 3) + 32 * s, dg = tid & 7;
        *(bf16x8*)&S[tl][dg * 8] =
            *(const bf16x8*)&qkv[((size_t)(b * SEQ + t0 + tl)) * QKV_N + 2 * D_MODEL + h * D_HEAD + dg * 8];
    }
    __syncthreads();
#pragma unroll
    for (int ii = 0; ii < 2; ii++) {
        int d = (tid >> 3) + 32 * ii, tg = tid & 7;
        bf16x8 v;
#pragma unroll
        for (int j = 0; j < 8; j++) v[j] = S[tg * 8 + j][d];
        *(bf16x8*)&vt[((size_t)bh * 64 + d) * SEQ + t0 + tg * 8] = v;
    }
}

// ---------------------------------------------------------------------------
// Flash attention (causal), paired q-tiles, swapped QK^T (S^T = K·Q^T),
// fully in-register softmax + P redistribution (no P LDS round-trip).
// Lane layout: softmax-land q = lane&15; oacc/out-land q = lhi*4+r (rows).
// ---------------------------------------------------------------------------
struct QState {
    bf16x8 qf[2];     // Q[q=lane&15, k-chunk lhi*8], chunks c=0,1
    float  m, l;      // running max (log2-scaled) & denom for q=lane&15
    f32x4  oacc[4];   // O[q=lhi*4+r, d=nd*16+lane&15]
};

__device__ __forceinline__ unsigned cvt_pk_bf16(float lo, float hi) {
    unsigned r;
    asm("v_cvt_pk_bf16_f32 %0, %1, %2" : "=v"(r) : "v"(lo), "v"(hi));
    return r;
}

__device__ __forceinline__ void attn_tile(QState& st,
                                          const short (*Ks)[64],
                                          const short (*Vs)[64],
                                          bool diag, int w, int lr, int lhi) {
    const int swz = lr & 7;
    // ---- S^T = K·Q^T : D[row=k=lhi*4+r (per ni), col=q=lane&15] ----
    f32x4 sa[4];
#pragma unroll
    for (int ni = 0; ni < 4; ni++)
#pragma unroll
        for (int e = 0; e < 4; e++) sa[ni][e] = 0.0f;
#pragma unroll
    for (int c = 0; c < 2; c++)
#pragma unroll
        for (int ni = 0; ni < 4; ni++) {
            bf16x8 kf = *(const bf16x8*)&Ks[ni * 16 + lr][((c * 4 + lhi) ^ swz) * 8];
            sa[ni] = __builtin_amdgcn_mfma_f32_16x16x32_bf16(kf, st.qf[c], sa[ni], 0, 0, 0);
        }

    if (diag) {
#pragma unroll
        for (int ni = 0; ni < 4; ni++)
#pragma unroll
            for (int r = 0; r < 4; r++)
                if (ni * 16 + lhi * 4 + r > w * 16 + lr) sa[ni][r] = -INFINITY;
    }

    // ---- row stats: in-lane over 16 + cross-lhi (2 shfl) ----
    float mx = sa[0][0];
#pragma unroll
    for (int ni = 0; ni < 4; ni++)
#pragma unroll
        for (int r = 0; r < 4; r++) mx = fmaxf(mx, sa[ni][r]);
    mx = fmaxf(mx, __shfl_xor(mx, 16, 64));
    mx = fmaxf(mx, __shfl_xor(mx, 32, 64));
    float smax = mx * SCL;

    // T13 defer-max: skip rescale while growth <= 8 (log2 units, P <= 256)
    if (!__all(smax <= st.m + 8.0f)) {
        float mnew = fmaxf(st.m, smax);
        float corr = __builtin_amdgcn_exp2f(st.m - mnew);
        st.m = mnew;
        st.l *= corr;
        float cT[4];
#pragma unroll
        for (int r = 0; r < 4; r++) cT[r] = __shfl(corr, lhi * 4 + r, 64);
#pragma unroll
        for (int nd = 0; nd < 4; nd++)
#pragma unroll
            for (int r = 0; r < 4; r++) st.oacc[nd][r] *= cT[r];
    }

    // ---- P = exp2(S*SCL - m), row-sum, pack to bf16 pairs ----
    float ls = 0.0f;
    unsigned pk[4][2];   // [ni][rp]: pair (p[ni][2rp], p[ni][2rp+1])
#pragma unroll
    for (int ni = 0; ni < 4; ni++) {
        float p0 = __builtin_amdgcn_exp2f(fmaf(sa[ni][0], SCL, -st.m));
        float p1 = __builtin_amdgcn_exp2f(fmaf(sa[ni][1], SCL, -st.m));
        float p2 = __builtin_amdgcn_exp2f(fmaf(sa[ni][2], SCL, -st.m));
        float p3 = __builtin_amdgcn_exp2f(fmaf(sa[ni][3], SCL, -st.m));
        ls += (p0 + p1) + (p2 + p3);
        pk[ni][0] = cvt_pk_bf16(p0, p1);
        pk[ni][1] = cvt_pk_bf16(p2, p3);
    }
    ls += __shfl_xor(ls, 16, 64);
    ls += __shfl_xor(ls, 32, 64);
    st.l += ls;

    // ---- redistribute pk across lhi groups into PV A-fragments ----
    // dest (c,t) at lhi=L holds k-pair k0=c*32+L*8+2t, sourced from
    // lhi_s=(2L+(t>>1))&3, reg pk[2c+(L>>1)][t&1].
    const bool b0 = lhi & 1, b1 = lhi & 2;
    bf16x8 pav[2];
#pragma unroll
    for (int c = 0; c < 2; c++) {
        union { unsigned u[4]; bf16x8 v; } pu;
#pragma unroll
        for (int rp = 0; rp < 2; rp++) {
            unsigned selfv = b1 ? pk[2 * c + 1][rp] : pk[2 * c][rp];
            unsigned othv  = b1 ? pk[2 * c][rp]     : pk[2 * c + 1][rp];
            unsigned r16 = __shfl_xor(selfv, 16, 64);
            unsigned r32 = __shfl_xor(othv, 32, 64);
            unsigned r48 = __shfl_xor(othv, 48, 64);
            unsigned low  = b1 ? (b0 ? r16 : r32) : (b0 ? r48 : selfv);
            unsigned high = b1 ? (b0 ? selfv : r48) : (b0 ? r32 : r16);
            pu.u[rp]     = low;    // t = 0,1
            pu.u[2 + rp] = high;   // t = 2,3
        }
        pav[c] = pu.v;
    }

    // ---- O += P·V : mfma(A=P, B=V) ----
#pragma unroll
    for (int c = 0; c < 2; c++)
#pragma unroll
        for (int nd = 0; nd < 4; nd++) {
            bf16x8 vb = *(const bf16x8*)&Vs[nd * 16 + lr][((c * 4 + lhi) ^ swz) * 8];
            st.oacc[nd] = __builtin_amdgcn_mfma_f32_16x16x32_bf16(pav[c], vb, st.oacc[nd], 0, 0, 0);
        }
}

__global__ __launch_bounds__(256) void attn_fwd(const short* __restrict__ qkv,
                                                const short* __restrict__ vt,
                                                unsigned short* __restrict__ out) {
    __shared__ __align__(16) short Ks[64][64];   // K tile  [kv][d]  (swizzled)
    __shared__ __align__(16) short Vs[64][64];   // V^T tile [d][kv] (swizzled)

    const int tid  = threadIdx.x;
    const int w    = tid >> 6;
    const int lane = tid & 63;
    const int lr   = lane & 15, lhi = lane >> 4;
    const int i    = blockIdx.x;                 // 0..31
    const int bh   = blockIdx.y;
    const int b    = bh / N_HEADS, h = bh % N_HEADS;
    const size_t rowbase = (size_t)b * SEQ;
    const int srow = tid >> 3, sg = tid & 7;

    const int qa0 = i * 64;                      // light q-tile
    const int qb0 = (NTILES - 1 - i) * 64;       // heavy q-tile

    QState sa_, sb_;
    {
        int qrowA = qa0 + w * 16 + lr;
        int qrowB = qb0 + w * 16 + lr;
        const short* pA = &qkv[(rowbase + qrowA) * QKV_N + h * D_HEAD];
        const short* pB = &qkv[(rowbase + qrowB) * QKV_N + h * D_HEAD];
        sa_.qf[0] = *(const bf16x8*)&pA[lhi * 8];
        sa_.qf[1] = *(const bf16x8*)&pA[32 + lhi * 8];
        sb_.qf[0] = *(const bf16x8*)&pB[lhi * 8];
        sb_.qf[1] = *(const bf16x8*)&pB[32 + lhi * 8];
    }
    sa_.m = -INFINITY; sa_.l = 0.0f;
    sb_.m = -INFINITY; sb_.l = 0.0f;
#pragma unroll
    for (int nd = 0; nd < 4; nd++)
#pragma unroll
        for (int r = 0; r < 4; r++) { sa_.oacc[nd][r] = 0.0f; sb_.oacc[nd][r] = 0.0f; }

    // T14: prefetch tile 0 into registers
    bf16x8 kp[2], vp[2];
#pragma unroll
    for (int s = 0; s < 2; s++) {
        int row = srow + 32 * s;
        kp[s] = *(const bf16x8*)&qkv[(rowbase + 0 + row) * QKV_N + D_MODEL + h * D_HEAD + sg * 8];
        vp[s] = *(const bf16x8*)&vt[((size_t)bh * 64 + row) * SEQ + 0 + sg * 8];
    }

    for (int j0 = 0; j0 <= qb0; j0 += 64) {
        __syncthreads();
#pragma unroll
        for (int s = 0; s < 2; s++) {
            int row = srow + 32 * s;
            int dst = (sg ^ (row & 7)) * 8;
            *(bf16x8*)&Ks[row][dst] = kp[s];
            *(bf16x8*)&Vs[row][dst] = vp[s];
        }
        {
            int jn = (j0 + 64 <= qb0) ? j0 + 64 : 0;
#pragma unroll
            for (int s = 0; s < 2; s++) {
                int row = srow + 32 * s;
                kp[s] = *(const bf16x8*)&qkv[(rowbase + jn + row) * QKV_N + D_MODEL + h * D_HEAD + sg * 8];
                vp[s] = *(const bf16x8*)&vt[((size_t)bh * 64 + row) * SEQ + jn + sg * 8];
            }
        }
        __syncthreads();

        attn_tile(sb_, Ks, Vs, j0 == qb0, w, lr, lhi);
        if (j0 <= qa0)
            attn_tile(sa_, Ks, Vs, j0 == qa0, w, lr, lhi);
    }

    // ---- epilogue: transpose l to row-land via bpermute, divide, store ----
    float lTA[4], lTB[4];
#pragma unroll
    for (int r = 0; r < 4; r++) {
        lTA[r] = 1.0f / __shfl(sa_.l, lhi * 4 + r, 64);
        lTB[r] = 1.0f / __shfl(sb_.l, lhi * 4 + r, 64);
    }
#pragma unroll
    for (int nd = 0; nd < 4; nd++)
#pragma unroll
        for (int r = 0; r < 4; r++) {
            int qrowA = qa0 + w * 16 + lhi * 4 + r;
            int qrowB = qb0 + w * 16 + lhi * 4 + r;
            out[(rowbase + qrowA) * D_MODEL + h * D_HEAD + nd * 16 + lr] =
                __bfloat16_as_ushort(__float2bfloat16(sa_.oacc[nd][r] * lTA[r]));
            out[(rowbase + qrowB) * D_MODEL + h * D_HEAD + nd * 16 + lr] =
                __bfloat16_as_ushort(__float2bfloat16(sb_.oacc[nd][r] * lTB[r]));
        }
}

// ---------------------------------------------------------------------------
extern "C" void kernel_launch(void* const* d_in, const int* in_sizes, int n_in,
                              void* d_out, int out_size, void* d_ws, size_t ws_size,
                              hipStream_t stream) {
    const float* x     = (const float*)d_in[0];
    const float* w_qkv = (const float*)d_in[1];
    const float* w_out = (const float*)d_in[2];
    float* outp        = (float*)d_out;

    char* ws = (char*)d_ws;
    size_t off = 0;
    auto alloc = [&](size_t bytes) -> void* {
        void* p = ws + off;
        off = (off + bytes + 255) & ~(size_t)255;
        return p;
    };
    unsigned short* xb    = (unsigned short*)alloc((size_t)MROWS * D_MODEL * 2);  // also attn out
    unsigned short* wqkvb = (unsigned short*)alloc((size_t)QKV_N * D_MODEL * 2);
    unsigned short* woutb = (unsigned short*)alloc((size_t)D_MODEL * D_MODEL * 2);
    unsigned short* qkvb  = (unsigned short*)alloc((size_t)MROWS * QKV_N * 2);
    unsigned short* vtb   = (unsigned short*)alloc((size_t)BATCH * N_HEADS * D_HEAD * SEQ * 2);

    {
        int n4 = MROWS * D_MODEL / 4;
        f32_to_bf16<<<(n4 + 255) / 256, 256, 0, stream>>>(x, xb, n4);
        n4 = QKV_N * D_MODEL / 4;
        f32_to_bf16<<<(n4 + 255) / 256, 256, 0, stream>>>(w_qkv, wqkvb, n4);
        n4 = D_MODEL * D_MODEL / 4;
        f32_to_bf16<<<(n4 + 255) / 256, 256, 0, stream>>>(w_out, woutb, n4);
    }

    // qkv = x @ w_qkv^T   (M=8192, N=2304, K=768) -> bf16
    gemm_bt<false><<<dim3(QKV_N / BN, MROWS / BM), 256, 0, stream>>>(
        (const short*)xb, (const short*)wqkvb, nullptr, qkvb, MROWS, QKV_N, D_MODEL);

    // V transpose: (b,t,h,d) -> [bh*64+d][t]
    v_transpose<<<dim3(SEQ / 64, BATCH * N_HEADS), 256, 0, stream>>>((const short*)qkvb, (short*)vtb);

    // attention (paired q-tiles), writes bf16 into xb (dead after QKV GEMM)
    attn_fwd<<<dim3(NTILES / 2, BATCH * N_HEADS), 256, 0, stream>>>(
        (const short*)qkvb, (const short*)vtb, xb);

    // out = attn @ w_out^T  (M=8192, N=768, K=768) -> f32
    gemm_bt<true><<<dim3(D_MODEL / BN, MROWS / BM), 256, 0, stream>>>(
        (const short*)xb, (const short*)woutb, outp, nullptr, MROWS, D_MODEL, D_MODEL);
}